// Round 4
// baseline (444.305 us; speedup 1.0000x reference)
//
#include <hip/hip_runtime.h>
#include <math.h>

// MS-SSIM loss, 5 levels, 11-tap separable Gaussian (sigma=1.5), VALID padding.
// Round 4: 4-map algebraic transform (a=x+y, b=x-y: p,q,u,v replace the 5
// moment maps exactly), float4-interleaved LDS intermediate (stride 35 float4
// rows -> conflict-free b128), v-pass reads 14 ds_read_b128 per thread.

#define TILE 32
#define TIN  42          // TILE + 10 (halo for 11-tap valid conv)
#define HBS4 35          // hb row stride in float4 units (560B -> uniform bank quads)

struct GWin { float w[11]; };

__global__ __launch_bounds__(256, 6)
void ssim_level_kernel(const float* __restrict__ X, const float* __restrict__ Y,
                       float* __restrict__ poolX, float* __restrict__ poolY,
                       float* __restrict__ accum,   // [0..95]=ssim sums, [96..191]=cs sums
                       int S, int outS, int doPool, GWin gw)
{
    __shared__ float4 hb[TIN * HBS4];   // hb[r][c] = {p, q, u, v}
    __shared__ float rs[4], rc[4];

    const int ch  = blockIdx.z;      // 0..95 (n*c)
    const int gx0 = blockIdx.x * TILE;
    const int gy0 = blockIdx.y * TILE;
    const int tid = threadIdx.x;

    const float* Xc = X + (size_t)ch * S * S;
    const float* Yc = Y + (size_t)ch * S * S;

    // ---- 2x2 avg-pool into next level (independent; loads overlap h-pass) ----
    if (doPool) {
        int pr = tid >> 4, pc = tid & 15;      // 16x16 pooled outputs per block
        int halfS = S >> 1;
        int py = (gy0 >> 1) + pr, px = (gx0 >> 1) + pc;
        int r = gy0 + 2 * pr, c = gx0 + 2 * pc;
        float2 x0 = *reinterpret_cast<const float2*>(Xc + (size_t)r * S + c);
        float2 x1 = *reinterpret_cast<const float2*>(Xc + (size_t)(r + 1) * S + c);
        float2 y0 = *reinterpret_cast<const float2*>(Yc + (size_t)r * S + c);
        float2 y1 = *reinterpret_cast<const float2*>(Yc + (size_t)(r + 1) * S + c);
        float xa = 0.25f * (x0.x + x0.y + x1.x + x1.y);
        float ya = 0.25f * (y0.x + y0.y + y1.x + y1.y);
        size_t o = (size_t)ch * halfS * halfS + (size_t)py * halfS + px;
        poolX[o] = xa;
        poolY[o] = ya;
    }

    // ---- horizontal 11-tap pass on 4 maps (a, b, a^2, b^2), direct global reads ----
    // 42 rows * 8 quad-groups = 336 groups of 4 outputs
    const bool interior = (gx0 + 44 <= S);   // block-uniform
    for (int g = tid; g < TIN * 8; g += 256) {
        int r  = g >> 3;
        int c4 = (g & 7) * 4;
        int gr = gy0 + r; if (gr > S - 1) gr = S - 1;   // clamped rows feed only invalid outputs
        const float* xrow = Xc + (size_t)gr * S;
        const float* yrow = Yc + (size_t)gr * S;
        float xv[16], yv[16];
        if (interior) {
            int gc = gx0 + c4;
            *reinterpret_cast<float4*>(&xv[0])  = *reinterpret_cast<const float4*>(xrow + gc);
            *reinterpret_cast<float4*>(&xv[4])  = *reinterpret_cast<const float4*>(xrow + gc + 4);
            *reinterpret_cast<float4*>(&xv[8])  = *reinterpret_cast<const float4*>(xrow + gc + 8);
            *reinterpret_cast<float4*>(&xv[12]) = *reinterpret_cast<const float4*>(xrow + gc + 12);
            *reinterpret_cast<float4*>(&yv[0])  = *reinterpret_cast<const float4*>(yrow + gc);
            *reinterpret_cast<float4*>(&yv[4])  = *reinterpret_cast<const float4*>(yrow + gc + 4);
            *reinterpret_cast<float4*>(&yv[8])  = *reinterpret_cast<const float4*>(yrow + gc + 8);
            *reinterpret_cast<float4*>(&yv[12]) = *reinterpret_cast<const float4*>(yrow + gc + 12);
        } else {
            #pragma unroll
            for (int i = 0; i < 14; ++i) {
                int gc = gx0 + c4 + i; if (gc > S - 1) gc = S - 1;  // clamped cols feed only invalid outputs
                xv[i] = xrow[gc];
                yv[i] = yrow[gc];
            }
            xv[14] = xv[15] = yv[14] = yv[15] = 0.f;
        }
        float av[14], bv[14], aa[14], bb[14];
        #pragma unroll
        for (int i = 0; i < 14; ++i) {
            av[i] = xv[i] + yv[i];
            bv[i] = xv[i] - yv[i];
            aa[i] = av[i] * av[i];
            bb[i] = bv[i] * bv[i];
        }
        float aP[4], aQ[4], aU[4], aV[4];
        #pragma unroll
        for (int j = 0; j < 4; ++j) { aP[j] = 0.f; aQ[j] = 0.f; aU[j] = 0.f; aV[j] = 0.f; }
        #pragma unroll
        for (int k = 0; k < 11; ++k) {
            float w = gw.w[k];
            #pragma unroll
            for (int j = 0; j < 4; ++j) {
                aP[j] += w * av[j + k];
                aQ[j] += w * bv[j + k];
                aU[j] += w * aa[j + k];
                aV[j] += w * bb[j + k];
            }
        }
        #pragma unroll
        for (int j = 0; j < 4; ++j)
            hb[r * HBS4 + c4 + j] = make_float4(aP[j], aQ[j], aU[j], aV[j]);
    }
    __syncthreads();

    // ---- vertical 11-tap pass: 1x4 vertical output group per thread ----
    const float C1 = 1e-4f, C2 = 9e-4f;
    float ssum = 0.f, csum = 0.f;
    {
        int c  = tid & 31;
        int r0 = (tid >> 5) * 4;            // 8 strips * 4 rows = 32
        float accP[4], accQ[4], accU[4], accV[4];
        #pragma unroll
        for (int j = 0; j < 4; ++j) { accP[j] = 0.f; accQ[j] = 0.f; accU[j] = 0.f; accV[j] = 0.f; }
        const float4* hbp = &hb[r0 * HBS4 + c];
        #pragma unroll
        for (int k = 0; k < 14; ++k) {
            float4 h = hbp[k * HBS4];
            #pragma unroll
            for (int j = 0; j < 4; ++j) {
                if (j <= k && k - j <= 10) {
                    float w = gw.w[k - j];
                    accP[j] += w * h.x;
                    accQ[j] += w * h.y;
                    accU[j] += w * h.z;
                    accV[j] += w * h.w;
                }
            }
        }
        int ox = gx0 + c;
        #pragma unroll
        for (int j = 0; j < 4; ++j) {
            int oy = gy0 + r0 + j;
            if (oy < outS && ox < outS) {
                float p = accP[j], q = accQ[j];
                float p2 = p * p, q2 = q * q;
                float hd = 0.5f * (p2 - q2);              // 2*mu12
                float hs = 0.5f * (p2 + q2);              // m1^2 + m2^2
                float ed = 0.5f * (accU[j] - accV[j]);    // 2*e12
                float es = 0.5f * (accU[j] + accV[j]);    // e11 + e22
                float num_s = hd + C1, den_s = hs + C1;
                float num_c = (ed - hd) + C2, den_c = (es - hs) + C2;
                float cs = num_c * __builtin_amdgcn_rcpf(den_c);
                float ss = num_s * __builtin_amdgcn_rcpf(den_s) * cs;
                ssum += ss;
                csum += cs;
            }
        }
    }

    // ---- block reduction + atomic accumulate ----
    for (int off = 32; off > 0; off >>= 1) {
        ssum += __shfl_down(ssum, off);
        csum += __shfl_down(csum, off);
    }
    int wid = tid >> 6, lane = tid & 63;
    if (lane == 0) { rs[wid] = ssum; rc[wid] = csum; }
    __syncthreads();
    if (tid == 0) {
        float s = rs[0] + rs[1] + rs[2] + rs[3];
        float c = rc[0] + rc[1] + rc[2] + rc[3];
        atomicAdd(&accum[ch], s);
        atomicAdd(&accum[96 + ch], c);
    }
}

__global__ void finalize_kernel(const float* __restrict__ accum, float* __restrict__ out)
{
    __shared__ float red[2];
    const int t = threadIdx.x;   // 128 threads
    const float w[5]   = {0.0448f, 0.2856f, 0.3001f, 0.2363f, 0.1333f};
    const float inv[5] = {1.f / (502.f * 502.f), 1.f / (246.f * 246.f),
                          1.f / (118.f * 118.f), 1.f / (54.f * 54.f),
                          1.f / (22.f * 22.f)};
    float ms = 0.f;
    if (t < 96) {
        ms = 1.f;
        #pragma unroll
        for (int l = 0; l < 5; ++l) {
            float v = (l < 4) ? accum[l * 192 + 96 + t] : accum[l * 192 + t];
            v *= inv[l];
            v = fmaxf(v, 0.f);
            ms *= powf(v, w[l]);
        }
    }
    for (int off = 32; off > 0; off >>= 1) ms += __shfl_down(ms, off);
    int wid = t >> 6, lane = t & 63;
    if (lane == 0) red[wid] = ms;
    __syncthreads();
    if (t == 0) out[0] = 1.f - (red[0] + red[1]) * (1.f / 96.f);
}

extern "C" void kernel_launch(void* const* d_in, const int* in_sizes, int n_in,
                              void* d_out, int out_size, void* d_ws, size_t ws_size,
                              hipStream_t stream)
{
    (void)in_sizes; (void)n_in; (void)out_size; (void)ws_size;
    const float* X = (const float*)d_in[0];
    const float* Y = (const float*)d_in[1];
    float* out = (float*)d_out;
    float* ws  = (float*)d_ws;

    // Gaussian window (size 11, sigma 1.5), normalized
    GWin gw;
    {
        double g[11], s = 0.0;
        for (int i = 0; i < 11; ++i) { double d = i - 5; g[i] = exp(-(d * d) / 4.5); s += g[i]; }
        for (int i = 0; i < 11; ++i) gw.w[i] = (float)(g[i] / s);
    }

    // workspace layout (floats)
    float* accum = ws;                 // 5 levels * 192
    size_t off = 1024;
    float* p1x = ws + off; off += (size_t)96 * 256 * 256;
    float* p1y = ws + off; off += (size_t)96 * 256 * 256;
    float* p2x = ws + off; off += (size_t)96 * 128 * 128;
    float* p2y = ws + off; off += (size_t)96 * 128 * 128;
    float* p3x = ws + off; off += (size_t)96 * 64 * 64;
    float* p3y = ws + off; off += (size_t)96 * 64 * 64;
    float* p4x = ws + off; off += (size_t)96 * 32 * 32;
    float* p4y = ws + off; off += (size_t)96 * 32 * 32;

    hipMemsetAsync(accum, 0, 5 * 192 * sizeof(float), stream);

    // level grids: tiles*32 == S at every level, so fused pooling exactly
    // covers the next level.
    ssim_level_kernel<<<dim3(16, 16, 96), 256, 0, stream>>>(X,   Y,   p1x, p1y, accum + 0,   512, 502, 1, gw);
    ssim_level_kernel<<<dim3(8,  8,  96), 256, 0, stream>>>(p1x, p1y, p2x, p2y, accum + 192, 256, 246, 1, gw);
    ssim_level_kernel<<<dim3(4,  4,  96), 256, 0, stream>>>(p2x, p2y, p3x, p3y, accum + 384, 128, 118, 1, gw);
    ssim_level_kernel<<<dim3(2,  2,  96), 256, 0, stream>>>(p3x, p3y, p4x, p4y, accum + 576, 64,  54,  1, gw);
    ssim_level_kernel<<<dim3(1,  1,  96), 256, 0, stream>>>(p4x, p4y, nullptr, nullptr, accum + 768, 32, 22, 0, gw);

    finalize_kernel<<<1, 128, 0, stream>>>(accum, out);
}

// Round 5
// 368.077 us; speedup vs baseline: 1.2071x; 1.2071x over previous
//
#include <hip/hip_runtime.h>
#include <math.h>

// MS-SSIM loss, 5 levels, 11-tap separable Gaussian (sigma=1.5), VALID padding.
// Round 5: strip-streaming kernel. Each block owns a 32-row strip x full width,
// iterates over 32-col chunks with software-pipelined global loads (next chunk's
// loads issued before the current chunk's v-pass, so HBM latency hides under
// compute + barriers). 4-map algebraic transform (p,q,u,v) as round 4.

#define TILE 32
#define TIN  42          // TILE + 10 (halo for 11-tap valid conv)
#define HBS4 35          // hb row stride in float4 units

struct GWin { float w[11]; };

__global__ __launch_bounds__(256, 3)
void ssim_strip_kernel(const float* __restrict__ X, const float* __restrict__ Y,
                       float* __restrict__ poolX, float* __restrict__ poolY,
                       float* __restrict__ accum,   // [0..95]=ssim sums, [96..191]=cs sums
                       int S, int outS, int doPool, GWin gw)
{
    __shared__ float4 hb[TIN * HBS4];   // hb[r][c] = {p, q, u, v}
    __shared__ float rs[4], rc[4];

    const int ch  = blockIdx.y;      // 0..95 (n*c)
    const int gy0 = blockIdx.x * TILE;
    const int tid = threadIdx.x;
    const int nt  = S >> 5;          // chunks across the width
    const int halfS = S >> 1;

    const float* Xc = X + (size_t)ch * S * S;
    const float* Yc = Y + (size_t)ch * S * S;

    // h-pass group A: rows 0..31; group B (tid<80): rows 32..41
    const int rA  = tid >> 3;            // 0..31
    const int cA4 = (tid & 7) << 2;      // 0,4,...,28
    const int rB  = (tid + 256) >> 3;    // 32..41
    const int cB4 = ((tid + 256) & 7) << 2;
    const bool hasB = (tid < 80);

    int grA = gy0 + rA; if (grA > S - 1) grA = S - 1;   // clamped rows feed only guarded outputs
    int grB = gy0 + rB; if (grB > S - 1) grB = S - 1;
    const float* xrowA = Xc + (size_t)grA * S;
    const float* yrowA = Yc + (size_t)grA * S;
    const float* xrowB = Xc + (size_t)grB * S;
    const float* yrowB = Yc + (size_t)grB * S;

    // pool mapping: 16x16 pooled outputs per chunk
    const int pr = tid >> 4, pc = tid & 15;
    const float* prx = Xc + (size_t)(gy0 + 2 * pr) * S;
    const float* pry = Yc + (size_t)(gy0 + 2 * pr) * S;

    // v-pass mapping: 1x4 vertical output group per thread
    const int vc  = tid & 31;
    const int vr0 = (tid >> 5) << 2;

    float xvA[16], yvA[16], xvB[16], yvB[16];
    float2 px0, px1, py0, py1;

    float ssum = 0.f, csum = 0.f;

    auto issue_loads = [&](int t) {
        const int x0 = t * TILE;
        if (x0 + 44 <= S) {          // interior chunk: pure float4 loads
            #pragma unroll
            for (int i = 0; i < 4; ++i) {
                *reinterpret_cast<float4*>(&xvA[4 * i]) = *reinterpret_cast<const float4*>(xrowA + x0 + cA4 + 4 * i);
                *reinterpret_cast<float4*>(&yvA[4 * i]) = *reinterpret_cast<const float4*>(yrowA + x0 + cA4 + 4 * i);
            }
            if (hasB) {
                #pragma unroll
                for (int i = 0; i < 4; ++i) {
                    *reinterpret_cast<float4*>(&xvB[4 * i]) = *reinterpret_cast<const float4*>(xrowB + x0 + cB4 + 4 * i);
                    *reinterpret_cast<float4*>(&yvB[4 * i]) = *reinterpret_cast<const float4*>(yrowB + x0 + cB4 + 4 * i);
                }
            }
        } else {                     // last chunk: clamped scalar loads
            #pragma unroll
            for (int i = 0; i < 14; ++i) {
                int gc = x0 + cA4 + i; if (gc > S - 1) gc = S - 1;
                xvA[i] = xrowA[gc];
                yvA[i] = yrowA[gc];
            }
            xvA[14] = xvA[15] = yvA[14] = yvA[15] = 0.f;
            if (hasB) {
                #pragma unroll
                for (int i = 0; i < 14; ++i) {
                    int gc = x0 + cB4 + i; if (gc > S - 1) gc = S - 1;
                    xvB[i] = xrowB[gc];
                    yvB[i] = yrowB[gc];
                }
                xvB[14] = xvB[15] = yvB[14] = yvB[15] = 0.f;
            }
        }
        if (doPool) {
            int c = x0 + 2 * pc;
            px0 = *reinterpret_cast<const float2*>(prx + c);
            px1 = *reinterpret_cast<const float2*>(prx + S + c);
            py0 = *reinterpret_cast<const float2*>(pry + c);
            py1 = *reinterpret_cast<const float2*>(pry + S + c);
        }
    };

    auto compute_h = [&](const float* xv, const float* yv, int r, int c4) {
        // P,U from a=x+y; then Q,V from b=x-y (halves live temps)
        float av[14], sq[14];
        #pragma unroll
        for (int i = 0; i < 14; ++i) { av[i] = xv[i] + yv[i]; sq[i] = av[i] * av[i]; }
        float aP[4] = {0, 0, 0, 0}, aU[4] = {0, 0, 0, 0};
        #pragma unroll
        for (int k = 0; k < 11; ++k) {
            float w = gw.w[k];
            #pragma unroll
            for (int j = 0; j < 4; ++j) { aP[j] += w * av[j + k]; aU[j] += w * sq[j + k]; }
        }
        #pragma unroll
        for (int i = 0; i < 14; ++i) { av[i] = xv[i] - yv[i]; sq[i] = av[i] * av[i]; }
        float aQ[4] = {0, 0, 0, 0}, aV[4] = {0, 0, 0, 0};
        #pragma unroll
        for (int k = 0; k < 11; ++k) {
            float w = gw.w[k];
            #pragma unroll
            for (int j = 0; j < 4; ++j) { aQ[j] += w * av[j + k]; aV[j] += w * sq[j + k]; }
        }
        #pragma unroll
        for (int j = 0; j < 4; ++j)
            hb[r * HBS4 + c4 + j] = make_float4(aP[j], aQ[j], aU[j], aV[j]);
    };

    issue_loads(0);

    const float C1 = 1e-4f, C2 = 9e-4f;

    for (int t = 0; t < nt; ++t) {
        // ---- h-pass for chunk t (waits on its loads) ----
        compute_h(xvA, yvA, rA, cA4);
        if (hasB) compute_h(xvB, yvB, rB, cB4);

        // consume pool regs before reissue
        float xa = 0.f, ya = 0.f;
        if (doPool) {
            xa = 0.25f * (px0.x + px0.y + px1.x + px1.y);
            ya = 0.25f * (py0.x + py0.y + py1.x + py1.y);
        }

        // ---- pipeline: issue chunk t+1 loads; they fly across barriers+v-pass ----
        if (t + 1 < nt) issue_loads(t + 1);

        // pool store (fire-and-forget)
        if (doPool) {
            size_t o = (size_t)ch * halfS * halfS
                     + (size_t)((gy0 >> 1) + pr) * halfS + ((t * TILE) >> 1) + pc;
            poolX[o] = xa;
            poolY[o] = ya;
        }

        __syncthreads();   // hb(t) writes visible

        // ---- v-pass for chunk t ----
        {
            float accP[4] = {0,0,0,0}, accQ[4] = {0,0,0,0};
            float accU[4] = {0,0,0,0}, accV[4] = {0,0,0,0};
            const float4* hbp = &hb[vr0 * HBS4 + vc];
            #pragma unroll
            for (int k = 0; k < 14; ++k) {
                float4 h = hbp[k * HBS4];
                #pragma unroll
                for (int j = 0; j < 4; ++j) {
                    if (j <= k && k - j <= 10) {
                        float w = gw.w[k - j];
                        accP[j] += w * h.x; accQ[j] += w * h.y;
                        accU[j] += w * h.z; accV[j] += w * h.w;
                    }
                }
            }
            int ox = t * TILE + vc;
            #pragma unroll
            for (int j = 0; j < 4; ++j) {
                int oy = gy0 + vr0 + j;
                if (oy < outS && ox < outS) {
                    float p = accP[j], q = accQ[j];
                    float p2 = p * p, q2 = q * q;
                    float hd = 0.5f * (p2 - q2);              // 2*mu12
                    float hs = 0.5f * (p2 + q2);              // m1^2 + m2^2
                    float ed = 0.5f * (accU[j] - accV[j]);    // 2*e12
                    float es = 0.5f * (accU[j] + accV[j]);    // e11 + e22
                    float cs = ((ed - hd) + C2) * __builtin_amdgcn_rcpf((es - hs) + C2);
                    float ss = (hd + C1) * __builtin_amdgcn_rcpf(hs + C1) * cs;
                    ssum += ss;
                    csum += cs;
                }
            }
        }
        __syncthreads();   // before hb(t+1) overwrite
    }

    // ---- block reduction + atomic accumulate ----
    for (int off = 32; off > 0; off >>= 1) {
        ssum += __shfl_down(ssum, off);
        csum += __shfl_down(csum, off);
    }
    int wid = tid >> 6, lane = tid & 63;
    if (lane == 0) { rs[wid] = ssum; rc[wid] = csum; }
    __syncthreads();
    if (tid == 0) {
        float s = rs[0] + rs[1] + rs[2] + rs[3];
        float c = rc[0] + rc[1] + rc[2] + rc[3];
        atomicAdd(&accum[ch], s);
        atomicAdd(&accum[96 + ch], c);
    }
}

__global__ void finalize_kernel(const float* __restrict__ accum, float* __restrict__ out)
{
    __shared__ float red[2];
    const int t = threadIdx.x;   // 128 threads
    const float w[5]   = {0.0448f, 0.2856f, 0.3001f, 0.2363f, 0.1333f};
    const float inv[5] = {1.f / (502.f * 502.f), 1.f / (246.f * 246.f),
                          1.f / (118.f * 118.f), 1.f / (54.f * 54.f),
                          1.f / (22.f * 22.f)};
    float ms = 0.f;
    if (t < 96) {
        ms = 1.f;
        #pragma unroll
        for (int l = 0; l < 5; ++l) {
            float v = (l < 4) ? accum[l * 192 + 96 + t] : accum[l * 192 + t];
            v *= inv[l];
            v = fmaxf(v, 0.f);
            ms *= powf(v, w[l]);
        }
    }
    for (int off = 32; off > 0; off >>= 1) ms += __shfl_down(ms, off);
    int wid = t >> 6, lane = t & 63;
    if (lane == 0) red[wid] = ms;
    __syncthreads();
    if (t == 0) out[0] = 1.f - (red[0] + red[1]) * (1.f / 96.f);
}

extern "C" void kernel_launch(void* const* d_in, const int* in_sizes, int n_in,
                              void* d_out, int out_size, void* d_ws, size_t ws_size,
                              hipStream_t stream)
{
    (void)in_sizes; (void)n_in; (void)out_size; (void)ws_size;
    const float* X = (const float*)d_in[0];
    const float* Y = (const float*)d_in[1];
    float* out = (float*)d_out;
    float* ws  = (float*)d_ws;

    // Gaussian window (size 11, sigma 1.5), normalized
    GWin gw;
    {
        double g[11], s = 0.0;
        for (int i = 0; i < 11; ++i) { double d = i - 5; g[i] = exp(-(d * d) / 4.5); s += g[i]; }
        for (int i = 0; i < 11; ++i) gw.w[i] = (float)(g[i] / s);
    }

    // workspace layout (floats)
    float* accum = ws;                 // 5 levels * 192
    size_t off = 1024;
    float* p1x = ws + off; off += (size_t)96 * 256 * 256;
    float* p1y = ws + off; off += (size_t)96 * 256 * 256;
    float* p2x = ws + off; off += (size_t)96 * 128 * 128;
    float* p2y = ws + off; off += (size_t)96 * 128 * 128;
    float* p3x = ws + off; off += (size_t)96 * 64 * 64;
    float* p3y = ws + off; off += (size_t)96 * 64 * 64;
    float* p4x = ws + off; off += (size_t)96 * 32 * 32;
    float* p4y = ws + off; off += (size_t)96 * 32 * 32;

    hipMemsetAsync(accum, 0, 5 * 192 * sizeof(float), stream);

    // one block per 32-row strip per channel; chunks stream across the width
    ssim_strip_kernel<<<dim3(16, 96), 256, 0, stream>>>(X,   Y,   p1x, p1y, accum + 0,   512, 502, 1, gw);
    ssim_strip_kernel<<<dim3(8,  96), 256, 0, stream>>>(p1x, p1y, p2x, p2y, accum + 192, 256, 246, 1, gw);
    ssim_strip_kernel<<<dim3(4,  96), 256, 0, stream>>>(p2x, p2y, p3x, p3y, accum + 384, 128, 118, 1, gw);
    ssim_strip_kernel<<<dim3(2,  96), 256, 0, stream>>>(p3x, p3y, p4x, p4y, accum + 576, 64,  54,  1, gw);
    ssim_strip_kernel<<<dim3(1,  96), 256, 0, stream>>>(p4x, p4y, nullptr, nullptr, accum + 768, 32, 22, 0, gw);

    finalize_kernel<<<1, 128, 0, stream>>>(accum, out);
}

// Round 6
// 249.822 us; speedup vs baseline: 1.7785x; 1.4734x over previous
//
#include <hip/hip_runtime.h>
#include <math.h>

// MS-SSIM loss, 5 levels, 11-tap separable Gaussian (sigma=1.5), VALID padding.
// Round 6: row-streaming strip kernel. Block = 256 threads owning a 256-col band
// x rowsPerSeg output rows. Streams input rows sequentially (2 rows/iter,
// contiguous coalesced loads -> few dense DRAM streams instead of 42 scattered
// row-segments), h-conv in registers from a 2-slot LDS row buffer, v-conv via a
// 12-deep static register ring (shift-by-2), fused 2x2 pooling.
// 4-map transform (a=x+y, b=x-y -> p,q,u,v) as rounds 4-5 (exact).

#define RW 272          // staged row width: 256 band cols + 10 halo + pad

struct GWin { float w[11]; };

__global__ __launch_bounds__(256)
void ssim_rows_kernel(const float* __restrict__ X, const float* __restrict__ Y,
                      float* __restrict__ poolX, float* __restrict__ poolY,
                      float* __restrict__ accum,   // [0..95]=ssim, [96..191]=cs
                      int S, int outS, int doPool, int rps, GWin gw)
{
    __shared__ float als[2][2][RW];   // [slot][row01][col]
    __shared__ float bls[2][2][RW];
    __shared__ float rs[4], rc[4];

    const int ch  = blockIdx.z;
    const int oy0 = blockIdx.x * rps;
    const int cb0 = blockIdx.y * 256;
    const int tid = threadIdx.x;
    const int halfS = S >> 1;
    const int NIT = (rps + 10) >> 1;     // iterations (2 input rows each)

    const float* Xc = X + (size_t)ch * S * S;
    const float* Yc = Y + (size_t)ch * S * S;

    // staging task decode (static per thread): 272 float2-tasks cover 2 rows x 136
    const int  r0_ = (tid < 136) ? 0 : 1;
    const int  c20 = (tid < 136) ? tid : tid - 136;
    const bool hasT1 = (tid < 16);
    const int  c21 = 120 + tid;          // task tid+256 -> row 1, c2 in [120,136)

    float2 sx0, sy0, sx1, sy1;           // prefetched global rows (task regs)

    auto issue = [&](int baseRow) {      // load rows baseRow, baseRow+1 -> regs
        {
            int gr = baseRow + r0_; if (gr > S - 1) gr = S - 1;
            const float* xr = Xc + (size_t)gr * S;
            const float* yr = Yc + (size_t)gr * S;
            int gc = cb0 + 2 * c20;
            if (gc + 1 < S) {
                sx0 = *reinterpret_cast<const float2*>(xr + gc);
                sy0 = *reinterpret_cast<const float2*>(yr + gc);
            } else {
                int g0 = gc < S ? gc : S - 1;
                sx0.x = xr[g0]; sx0.y = xr[S - 1];
                sy0.x = yr[g0]; sy0.y = yr[S - 1];
            }
        }
        if (hasT1) {
            int gr = baseRow + 1; if (gr > S - 1) gr = S - 1;
            const float* xr = Xc + (size_t)gr * S;
            const float* yr = Yc + (size_t)gr * S;
            int gc = cb0 + 2 * c21;
            if (gc + 1 < S) {
                sx1 = *reinterpret_cast<const float2*>(xr + gc);
                sy1 = *reinterpret_cast<const float2*>(yr + gc);
            } else {
                int g0 = gc < S ? gc : S - 1;
                sx1.x = xr[g0]; sx1.y = xr[S - 1];
                sy1.x = yr[g0]; sy1.y = yr[S - 1];
            }
        }
    };
    auto write_slot = [&](int sl) {      // regs -> LDS as a=x+y, b=x-y
        *reinterpret_cast<float2*>(&als[sl][r0_][2 * c20]) =
            make_float2(sx0.x + sy0.x, sx0.y + sy0.y);
        *reinterpret_cast<float2*>(&bls[sl][r0_][2 * c20]) =
            make_float2(sx0.x - sy0.x, sx0.y - sy0.y);
        if (hasT1) {
            *reinterpret_cast<float2*>(&als[sl][1][2 * c21]) =
                make_float2(sx1.x + sy1.x, sx1.y + sy1.y);
            *reinterpret_cast<float2*>(&bls[sl][1][2 * c21]) =
                make_float2(sx1.x - sy1.x, sx1.y - sy1.y);
        }
    };

    // pending v-conv partials: 12 rows x 4 maps (P,Q,U,V), all static-indexed
    float pend[48];
    #pragma unroll
    for (int i = 0; i < 48; ++i) pend[i] = 0.f;

    float ssum = 0.f, csum = 0.f;
    const float C1 = 1e-4f, C2 = 9e-4f;
    const int hc = cb0 + tid;            // this thread's output column

    // prologue
    issue(oy0);
    write_slot(0);
    issue(oy0 + 2);
    __syncthreads();

    for (int k = 0; k < NIT; ++k) {
        const int sl = k & 1;
        if (k + 1 < NIT) {
            write_slot(sl ^ 1);          // rows oy0+2(k+1) (regs from iter k-1)
            if (k + 3 <= NIT) issue(oy0 + 2 * (k + 2));
        }

        // ---- h-conv for the 2 staged rows ----
        float hP[2], hQ[2], hU[2], hV[2];
        #pragma unroll
        for (int rr = 0; rr < 2; ++rr) {
            float P = 0.f, Q = 0.f, U = 0.f, V = 0.f;
            #pragma unroll
            for (int t = 0; t < 11; ++t) {
                float w = gw.w[t];
                float a = als[sl][rr][tid + t];
                float b = bls[sl][rr][tid + t];
                P += w * a; U += w * (a * a);
                Q += w * b; V += w * (b * b);
            }
            hP[rr] = P; hQ[rr] = Q; hU[rr] = U; hV[rr] = V;
        }

        // ---- v-accumulate into pending ring ----
        #pragma unroll
        for (int j = 0; j <= 10; ++j) {          // row r contributes w[10-j] -> pend[j]
            float w = gw.w[10 - j];
            pend[4 * j + 0] += w * hP[0];
            pend[4 * j + 1] += w * hQ[0];
            pend[4 * j + 2] += w * hU[0];
            pend[4 * j + 3] += w * hV[0];
        }
        #pragma unroll
        for (int j = 1; j <= 11; ++j) {          // row r+1 contributes w[11-j] -> pend[j]
            float w = gw.w[11 - j];
            pend[4 * j + 0] += w * hP[1];
            pend[4 * j + 1] += w * hQ[1];
            pend[4 * j + 2] += w * hU[1];
            pend[4 * j + 3] += w * hV[1];
        }

        // ---- emit 2 finished output rows ----
        if (k >= 5) {
            #pragma unroll
            for (int e = 0; e < 2; ++e) {
                int orow = oy0 + 2 * k - 10 + e;
                float p = pend[4 * e + 0], q = pend[4 * e + 1];
                float u = pend[4 * e + 2], v = pend[4 * e + 3];
                float p2 = p * p, q2 = q * q;
                float hd = 0.5f * (p2 - q2);          // 2*mu12
                float hs = 0.5f * (p2 + q2);          // mu1^2 + mu2^2
                float ed = 0.5f * (u - v);            // 2*e12
                float es = 0.5f * (u + v);            // e11 + e22
                float cs = ((ed - hd) + C2) * __builtin_amdgcn_rcpf((es - hs) + C2);
                float ss = (hd + C1) * __builtin_amdgcn_rcpf(hs + C1) * cs;
                if (orow < outS && hc < outS) { ssum += ss; csum += cs; }
            }
        }

        // ---- shift ring by 2 ----
        #pragma unroll
        for (int j = 0; j < 40; ++j) pend[j] = pend[j + 8];
        #pragma unroll
        for (int j = 40; j < 48; ++j) pend[j] = 0.f;

        // ---- 2x2 pool of the 2 staged rows ----
        if (doPool && tid < 128 && k < (rps >> 1)) {
            int pc = (cb0 >> 1) + tid;
            if (pc < halfS) {
                float2 a0 = *reinterpret_cast<const float2*>(&als[sl][0][2 * tid]);
                float2 a1 = *reinterpret_cast<const float2*>(&als[sl][1][2 * tid]);
                float2 b0 = *reinterpret_cast<const float2*>(&bls[sl][0][2 * tid]);
                float2 b1 = *reinterpret_cast<const float2*>(&bls[sl][1][2 * tid]);
                float sa = a0.x + a0.y + a1.x + a1.y;
                float sb = b0.x + b0.y + b1.x + b1.y;
                int prow = (oy0 >> 1) + k;
                size_t o = (size_t)ch * halfS * halfS + (size_t)prow * halfS + pc;
                poolX[o] = 0.125f * (sa + sb);
                poolY[o] = 0.125f * (sa - sb);
            }
        }

        __syncthreads();
    }

    // ---- block reduction + atomic accumulate ----
    for (int off = 32; off > 0; off >>= 1) {
        ssum += __shfl_down(ssum, off);
        csum += __shfl_down(csum, off);
    }
    int wid = tid >> 6, lane = tid & 63;
    if (lane == 0) { rs[wid] = ssum; rc[wid] = csum; }
    __syncthreads();
    if (tid == 0) {
        float s = rs[0] + rs[1] + rs[2] + rs[3];
        float c = rc[0] + rc[1] + rc[2] + rc[3];
        atomicAdd(&accum[ch], s);
        atomicAdd(&accum[96 + ch], c);
    }
}

__global__ void finalize_kernel(const float* __restrict__ accum, float* __restrict__ out)
{
    __shared__ float red[2];
    const int t = threadIdx.x;   // 128 threads
    const float w[5]   = {0.0448f, 0.2856f, 0.3001f, 0.2363f, 0.1333f};
    const float inv[5] = {1.f / (502.f * 502.f), 1.f / (246.f * 246.f),
                          1.f / (118.f * 118.f), 1.f / (54.f * 54.f),
                          1.f / (22.f * 22.f)};
    float ms = 0.f;
    if (t < 96) {
        ms = 1.f;
        #pragma unroll
        for (int l = 0; l < 5; ++l) {
            float v = (l < 4) ? accum[l * 192 + 96 + t] : accum[l * 192 + t];
            v *= inv[l];
            v = fmaxf(v, 0.f);
            ms *= powf(v, w[l]);
        }
    }
    for (int off = 32; off > 0; off >>= 1) ms += __shfl_down(ms, off);
    int wid = t >> 6, lane = t & 63;
    if (lane == 0) red[wid] = ms;
    __syncthreads();
    if (t == 0) out[0] = 1.f - (red[0] + red[1]) * (1.f / 96.f);
}

extern "C" void kernel_launch(void* const* d_in, const int* in_sizes, int n_in,
                              void* d_out, int out_size, void* d_ws, size_t ws_size,
                              hipStream_t stream)
{
    (void)in_sizes; (void)n_in; (void)out_size; (void)ws_size;
    const float* X = (const float*)d_in[0];
    const float* Y = (const float*)d_in[1];
    float* out = (float*)d_out;
    float* ws  = (float*)d_ws;

    // Gaussian window (size 11, sigma 1.5), normalized
    GWin gw;
    {
        double g[11], s = 0.0;
        for (int i = 0; i < 11; ++i) { double d = i - 5; g[i] = exp(-(d * d) / 4.5); s += g[i]; }
        for (int i = 0; i < 11; ++i) gw.w[i] = (float)(g[i] / s);
    }

    // workspace layout (floats)
    float* accum = ws;                 // 5 levels * 192
    size_t off = 1024;
    float* p1x = ws + off; off += (size_t)96 * 256 * 256;
    float* p1y = ws + off; off += (size_t)96 * 256 * 256;
    float* p2x = ws + off; off += (size_t)96 * 128 * 128;
    float* p2y = ws + off; off += (size_t)96 * 128 * 128;
    float* p3x = ws + off; off += (size_t)96 * 64 * 64;
    float* p3y = ws + off; off += (size_t)96 * 64 * 64;
    float* p4x = ws + off; off += (size_t)96 * 32 * 32;
    float* p4y = ws + off; off += (size_t)96 * 32 * 32;

    hipMemsetAsync(accum, 0, 5 * 192 * sizeof(float), stream);

    auto launch = [&](const float* x, const float* y, float* px_, float* py_,
                      float* acc, int S, int outS, int pool) {
        int rps = (S >= 512) ? 64 : 32;               // output rows per block
        dim3 g((S + rps - 1) / rps, (S + 255) / 256, 96);
        ssim_rows_kernel<<<g, 256, 0, stream>>>(x, y, px_, py_, acc, S, outS, pool, rps, gw);
    };

    launch(X,   Y,   p1x, p1y, accum + 0,   512, 502, 1);
    launch(p1x, p1y, p2x, p2y, accum + 192, 256, 246, 1);
    launch(p2x, p2y, p3x, p3y, accum + 384, 128, 118, 1);
    launch(p3x, p3y, p4x, p4y, accum + 576, 64,  54,  1);
    launch(p4x, p4y, nullptr, nullptr, accum + 768, 32, 22, 0);

    finalize_kernel<<<1, 128, 0, stream>>>(accum, out);
}